// Round 4
// baseline (724.395 us; speedup 1.0000x reference)
//
#include <hip/hip_runtime.h>
#include <hip/hip_bf16.h>
#include <float.h>

#define BB 8
#define DD 384
#define NQ 2048
#define NK 2048
#define NEG 0.2f

// ============================ KNN ============================
// 4 threads per query, each scans a contiguous 512-key chunk (chunk order
// preserves ascending-index tie semantics), leader merges via LDS.
// Keys staged as float4(x,y,z,|k|^2): one ds_read_b128 broadcast per iter.
#define GROUPS 4
#define CHUNK  512              // NK / GROUPS
#define QPB    64               // queries per block (256 threads / 4 groups)

// stable top-8 insert: pos = count(list <= dist) -> ties keep earlier index
#define INSERT8(BD, BI, DIST, IDX)                                    \
  {                                                                   \
    int pos = 0;                                                      \
    _Pragma("unroll")                                                 \
    for (int s = 0; s < 8; ++s) pos += (BD[s] <= (DIST)) ? 1 : 0;     \
    _Pragma("unroll")                                                 \
    for (int s = 7; s >= 1; --s) {                                    \
      bool c = BD[s - 1] > (DIST);                                    \
      BD[s] = c ? BD[s - 1] : BD[s];                                  \
      BI[s] = c ? BI[s - 1] : BI[s];                                  \
    }                                                                 \
    _Pragma("unroll")                                                 \
    for (int s = 0; s < 8; ++s) if (s == pos) { BD[s] = (DIST); BI[s] = (IDX); } \
  }

__global__ __launch_bounds__(256) void knn_kernel(
    const float* __restrict__ qc,   // (B,3,NQ)
    const float* __restrict__ kc,   // (B,3,NK)
    int* __restrict__ idx)          // (B,NQ,8)
{
  __shared__ float4 ksm[GROUPS][CHUNK + 1]; // +1 pad: chunks start on banks 0/4/8/12
  __shared__ float  md[QPB][GROUPS * 8 + 1]; // +1 pad: leader reads conflict-free
  __shared__ int    mi[QPB][GROUPS * 8 + 1];

  const int b = blockIdx.y;
  const int t = threadIdx.x;

  const float* kcb = kc + (size_t)b * 3 * NK;
  for (int i = t; i < NK; i += 256) {
    float x = kcb[i], y = kcb[NK + i], z = kcb[2 * NK + i];
    ksm[i >> 9][i & (CHUNK - 1)] = make_float4(x, y, z, (x * x + y * y) + z * z);
  }
  __syncthreads();

  const int g  = t & 3;
  const int ql = t >> 2;                 // 0..63
  const int q  = blockIdx.x * QPB + ql;
  const float* qcb = qc + (size_t)b * 3 * NQ;
  const float qx = qcb[q], qy = qcb[NQ + q], qz = qcb[2 * NQ + q];
  const float q2 = (qx * qx + qy * qy) + qz * qz;

  float bd[8]; int bi[8];
  #pragma unroll
  for (int s = 0; s < 8; ++s) { bd[s] = FLT_MAX; bi[s] = 0; }

  const int jbase = g * CHUNK;
  for (int jj = 0; jj < CHUNK; ++jj) {
    float4 kv = ksm[g][jj];
    float inner = (qx * kv.x + qy * kv.y) + qz * kv.z;
    float dist  = (q2 - 2.0f * inner) + kv.w;
    if (dist < bd[7]) INSERT8(bd, bi, dist, jbase + jj);
  }

  #pragma unroll
  for (int s = 0; s < 8; ++s) { md[ql][g * 8 + s] = bd[s]; mi[ql][g * 8 + s] = bi[s]; }
  __syncthreads();

  if (g == 0) {
    // own list (group 0) is the init; insert groups 1..3 in index order (stable)
    for (int c = 8; c < 32; ++c) {
      float dist = md[ql][c];
      if (dist < bd[7]) { int ki = mi[ql][c]; INSERT8(bd, bi, dist, ki); }
    }
    int* op = idx + ((size_t)b * NQ + q) * 8;
    #pragma unroll
    for (int s = 0; s < 8; ++s) op[s] = bi[s];
  }
}

// ===================== Fused projection GEMMs =====================
// z = blockIdx.z in [0,16): b = z&7, mode = z>>3
//   mode 0: pk[b][n][d] = sum_f kf[b][f][n] * W[d][f]
//   mode 1: pq[b][n][d] = sum_f qf[b][f][n] * (W[d][D+f]-W[d][f]) + bias[d]
// 768 blocks = 3/CU; reg-prefetch of tile kt+1 overlaps HBM latency w/ FMAs.
// Thread map: td = t&15 (d fast) -> epilogue stores 256B-contiguous per row.
__global__ __launch_bounds__(256, 4) void proj_gemm_all(
    const float* __restrict__ kf,   // (B, D, NK)
    const float* __restrict__ qf,   // (B, D, NQ)
    const float* __restrict__ W,    // (D, 2D) row-major
    const float* __restrict__ bias, // (D)
    float* __restrict__ pk,         // (B, NK, D)
    float* __restrict__ pq)         // (B, NQ, D)
{
  __shared__ float At[16][128];   // [f][n]
  __shared__ float Bt[16][132];   // [f][d], padded: 2-way max on transpose store

  const int t    = threadIdx.x;
  const int z    = blockIdx.z;
  const int b    = z & 7;
  const int mode = z >> 3;
  const int n0 = blockIdx.x * 128;
  const int d0 = blockIdx.y * 128;
  const int td = t & 15;          // d fast: coalesced epilogue
  const int tn = t >> 4;

  float acc[8][8];
  #pragma unroll
  for (int i = 0; i < 8; ++i)
    #pragma unroll
    for (int j = 0; j < 8; ++j) acc[i][j] = 0.f;

  const float* feats = mode ? qf : kf;
  float* out = mode ? pq : pk;
  const float* fb = feats + (size_t)b * DD * 2048;

  const int ar  = t >> 5;         // 0..7  (A row within half-tile)
  const int ac  = (t & 31) * 4;   // 0..124
  const int bdl = t >> 2;         // 0..63 (B d within half-tile)
  const int bf  = (t & 3) * 4;    // f offset 0/4/8/12

  float4 sa0, sa1, sw1[2], sw2[2];

#define PREFETCH(KT)                                                          \
  {                                                                           \
    sa0 = *(const float4*)&fb[(size_t)((KT) + ar) * 2048 + n0 + ac];          \
    sa1 = *(const float4*)&fb[(size_t)((KT) + ar + 8) * 2048 + n0 + ac];      \
    _Pragma("unroll")                                                         \
    for (int h = 0; h < 2; ++h) {                                             \
      const float* wrow = W + (size_t)(d0 + bdl + h * 64) * (2 * DD) + (KT) + bf; \
      sw1[h] = *(const float4*)wrow;                                          \
      if (mode) sw2[h] = *(const float4*)(wrow + DD);                         \
    }                                                                         \
  }

  PREFETCH(0);

  for (int kt = 0; kt < DD; kt += 16) {
    *(float4*)&At[ar][ac]     = sa0;
    *(float4*)&At[ar + 8][ac] = sa1;
    #pragma unroll
    for (int h = 0; h < 2; ++h) {
      int d = bdl + h * 64;
      float4 w = sw1[h];
      if (mode) {
        w.x = sw2[h].x - w.x; w.y = sw2[h].y - w.y;
        w.z = sw2[h].z - w.z; w.w = sw2[h].w - w.w;
      }
      Bt[bf + 0][d] = w.x; Bt[bf + 1][d] = w.y;
      Bt[bf + 2][d] = w.z; Bt[bf + 3][d] = w.w;
    }
    __syncthreads();

    if (kt + 16 < DD) PREFETCH(kt + 16);   // overlap global latency w/ compute

    #pragma unroll
    for (int k = 0; k < 16; ++k) {
      float a[8], bb[8];
      *(float4*)&a[0]  = *(const float4*)&At[k][tn * 4];        // broadcast (free)
      *(float4*)&a[4]  = *(const float4*)&At[k][tn * 4 + 64];
      *(float4*)&bb[0] = *(const float4*)&Bt[k][td * 4];        // 2-way (free)
      *(float4*)&bb[4] = *(const float4*)&Bt[k][td * 4 + 64];
      #pragma unroll
      for (int i = 0; i < 8; ++i)
        #pragma unroll
        for (int j = 0; j < 8; ++j)
          acc[i][j] = fmaf(a[i], bb[j], acc[i][j]);
    }
    __syncthreads();
  }
#undef PREFETCH

  float blo[4], bhi[4];
  if (mode) {
    *(float4*)blo = *(const float4*)&bias[d0 + td * 4];
    *(float4*)bhi = *(const float4*)&bias[d0 + td * 4 + 64];
  }

  float* ob = out + (size_t)b * 2048 * DD;
  #pragma unroll
  for (int i = 0; i < 8; ++i) {
    int n = n0 + tn * 4 + (i & 3) + ((i >= 4) ? 64 : 0);
    float4 c0, c1;
    c0.x = acc[i][0]; c0.y = acc[i][1]; c0.z = acc[i][2]; c0.w = acc[i][3];
    c1.x = acc[i][4]; c1.y = acc[i][5]; c1.z = acc[i][6]; c1.w = acc[i][7];
    if (mode) {
      c0.x += blo[0]; c0.y += blo[1]; c0.z += blo[2]; c0.w += blo[3];
      c1.x += bhi[0]; c1.y += bhi[1]; c1.z += bhi[2]; c1.w += bhi[3];
    }
    *(float4*)&ob[(size_t)n * DD + d0 + td * 4]      = c0;
    *(float4*)&ob[(size_t)n * DD + d0 + td * 4 + 64] = c1;
  }
}

// ============== Gather + max over 8 neighbors + LeakyReLU ==============
// max_k LReLU(PK_k + PQ) = LReLU(max_k PK_k + PQ)  (LReLU monotone)
// float4 lanes: 96 lanes/query, 4 queries per 384-thread block.
__global__ __launch_bounds__(384) void gather_max_kernel(
    const float4* __restrict__ pk4,  // (B, NK, 96)
    const float4* __restrict__ pq4,  // (B, NQ, 96)
    const int* __restrict__ idx,     // (B, NQ, 8)
    float4* __restrict__ out4)       // (B, NQ, 96)
{
  const int t   = threadIdx.x;
  const int bq0 = blockIdx.x * 4;
  __shared__ int nb[4][8];
  if (t < 32) nb[t >> 3][t & 7] = idx[(size_t)(bq0 + (t >> 3)) * 8 + (t & 7)];
  __syncthreads();

  const int q_l = t / 96;            // 0..3
  const int dv  = t - q_l * 96;      // 0..95
  const int bq  = bq0 + q_l;
  const int b   = bq >> 11;          // NQ = 2048
  const float4* pkb = pk4 + (size_t)b * NK * 96;

  float4 m = make_float4(-FLT_MAX, -FLT_MAX, -FLT_MAX, -FLT_MAX);
  #pragma unroll
  for (int s = 0; s < 8; ++s) {
    float4 v = pkb[(size_t)nb[q_l][s] * 96 + dv];
    m.x = fmaxf(m.x, v.x); m.y = fmaxf(m.y, v.y);
    m.z = fmaxf(m.z, v.z); m.w = fmaxf(m.w, v.w);
  }
  float4 c = pq4[(size_t)bq * 96 + dv];
  float4 r;
  r.x = m.x + c.x; r.y = m.y + c.y; r.z = m.z + c.z; r.w = m.w + c.w;
  r.x = (r.x >= 0.f) ? r.x : NEG * r.x;
  r.y = (r.y >= 0.f) ? r.y : NEG * r.y;
  r.z = (r.z >= 0.f) ? r.z : NEG * r.z;
  r.w = (r.w >= 0.f) ? r.w : NEG * r.w;
  out4[(size_t)bq * 96 + dv] = r;
}

extern "C" void kernel_launch(void* const* d_in, const int* in_sizes, int n_in,
                              void* d_out, int out_size, void* d_ws, size_t ws_size,
                              hipStream_t stream) {
  const float* qc   = (const float*)d_in[0];
  const float* qf   = (const float*)d_in[1];
  const float* kc   = (const float*)d_in[2];
  const float* kf   = (const float*)d_in[3];
  const float* W    = (const float*)d_in[4];
  const float* bias = (const float*)d_in[5];
  float* out = (float*)d_out;

  char* ws = (char*)d_ws;
  float* pk = (float*)ws;                                   // B*NK*D f32 = 25.2 MB
  float* pq = (float*)(ws + (size_t)BB * NK * DD * 4);      // B*NQ*D f32 = 25.2 MB
  int*   ix = (int*)  (ws + (size_t)2 * BB * NK * DD * 4);  // B*NQ*8 i32 = 0.5 MB

  knn_kernel<<<dim3(NQ / QPB, BB), 256, 0, stream>>>(qc, kc, ix);
  proj_gemm_all<<<dim3(2048 / 128, DD / 128, 2 * BB), 256, 0, stream>>>(kf, qf, W, bias, pk, pq);
  gather_max_kernel<<<dim3(BB * NQ / 4), 384, 0, stream>>>(
      (const float4*)pk, (const float4*)pq, ix, (float4*)out);
}